// Round 1
// 173.032 us; speedup vs baseline: 1.0025x; 1.0025x over previous
//
#include <hip/hip_runtime.h>
#include <hip/hip_bf16.h>
#include <hip/hip_fp16.h>

#define FEAT 2048
#define NCLS 751
#define NPAD 768
#define NPRB 64
#define NGAL 256
#define WSCALE 256.0f

typedef _Float16 f16x8 __attribute__((ext_vector_type(8)));
typedef float f32x4 __attribute__((ext_vector_type(4)));

__device__ __forceinline__ unsigned short f2h_u(float x) {
  union { _Float16 h; unsigned short u; } v;
  v.h = (_Float16)x;
  return v.u;
}

// ---------------------------------------------------------------------------
// Kernel 1: per-feature moments of probe/gallery -> BN scale s[f], shift t[f]
// mean[f] = E_pg[(p-g)^2] = M2p - 2 M1p M1g + M2g   (exact, cross-product)
// E[d^2]  = M4p - 4 M3p M1g + 6 M2p M2g - 4 M1p M3g + M4g
// ---------------------------------------------------------------------------
__global__ void stats_kernel(const float* __restrict__ P, const float* __restrict__ G,
                             const float* __restrict__ gamma, const float* __restrict__ beta,
                             float* __restrict__ st) {
  int fx = threadIdx.x & 31, ry = threadIdx.x >> 5;
  int f = blockIdx.x * 32 + fx;
  float a1 = 0, a2 = 0, a3 = 0, a4 = 0;
  for (int r = ry; r < NPRB; r += 8) {
    float x = P[r * FEAT + f], x2 = x * x;
    a1 += x; a2 += x2; a3 += x2 * x; a4 += x2 * x2;
  }
  float b1 = 0, b2 = 0, b3 = 0, b4 = 0;
  for (int r = ry; r < NGAL; r += 8) {
    float x = G[r * FEAT + f], x2 = x * x;
    b1 += x; b2 += x2; b3 += x2 * x; b4 += x2 * x2;
  }
  __shared__ float red[8][8][32];
  float vals[8] = {a1, a2, a3, a4, b1, b2, b3, b4};
#pragma unroll
  for (int m = 0; m < 8; ++m) red[m][ry][fx] = vals[m];
  __syncthreads();
  if (ry == 0) {
    float mm[8];
#pragma unroll
    for (int m = 0; m < 8; ++m) {
      float sum = 0.f;
#pragma unroll
      for (int r = 0; r < 8; ++r) sum += red[m][r][fx];
      mm[m] = sum;
    }
    float M1p = mm[0] * (1.f / NPRB), M2p = mm[1] * (1.f / NPRB);
    float M3p = mm[2] * (1.f / NPRB), M4p = mm[3] * (1.f / NPRB);
    float M1g = mm[4] * (1.f / NGAL), M2g = mm[5] * (1.f / NGAL);
    float M3g = mm[6] * (1.f / NGAL), M4g = mm[7] * (1.f / NGAL);
    float mean = M2p - 2.f * M1p * M1g + M2g;
    float Ed2 = M4p - 4.f * M3p * M1g + 6.f * M2p * M2g - 4.f * M1p * M3g + M4g;
    float var = Ed2 - mean * mean;
    float sv = gamma[f] / sqrtf(var + 1e-5f);
    st[f] = sv;
    st[FEAT + f] = beta[f] - mean * sv;  // t[f]
  }
}

// ---------------------------------------------------------------------------
// Kernel 2 (fused): per class c:
//   Wp[c,f] = W[c,f] * s[f] * WSCALE (f16), bp[c] = b[c] + sum_f t[f] W[c,f]
// One block per padded class row; W read exactly once.
// ---------------------------------------------------------------------------
__global__ void prepw_kernel(const float* __restrict__ W, const float* __restrict__ b,
                             const float* __restrict__ st,
                             unsigned short* __restrict__ Wp, float* __restrict__ bp) {
  int c = blockIdx.x;
  int f = threadIdx.x * 8;
  float4 w0 = make_float4(0.f, 0.f, 0.f, 0.f), w1 = w0;
  if (c < NCLS) {
    const float4* wsrc = (const float4*)(W + (size_t)c * FEAT + f);
    w0 = wsrc[0]; w1 = wsrc[1];
  }
  const float4* s4 = (const float4*)(st + f);
  float4 s0 = s4[0], s1 = s4[1];
  const float4* t4 = (const float4*)(st + FEAT + f);
  float4 t0 = t4[0], t1 = t4[1];
  uint4 u;
  u.x = (unsigned int)f2h_u(w0.x * s0.x * WSCALE) | ((unsigned int)f2h_u(w0.y * s0.y * WSCALE) << 16);
  u.y = (unsigned int)f2h_u(w0.z * s0.z * WSCALE) | ((unsigned int)f2h_u(w0.w * s0.w * WSCALE) << 16);
  u.z = (unsigned int)f2h_u(w1.x * s1.x * WSCALE) | ((unsigned int)f2h_u(w1.y * s1.y * WSCALE) << 16);
  u.w = (unsigned int)f2h_u(w1.z * s1.z * WSCALE) | ((unsigned int)f2h_u(w1.w * s1.w * WSCALE) << 16);
  *(uint4*)(Wp + (size_t)c * FEAT + f) = u;
  float acc = t0.x * w0.x + t0.y * w0.y + t0.z * w0.z + t0.w * w0.w +
              t1.x * w1.x + t1.y * w1.y + t1.z * w1.z + t1.w * w1.w;
#pragma unroll
  for (int off = 32; off > 0; off >>= 1) acc += __shfl_down(acc, off, 64);
  __shared__ float r[4];
  int wave = threadIdx.x >> 6, lane = threadIdx.x & 63;
  if (lane == 0) r[wave] = acc;
  __syncthreads();
  if (threadIdx.x == 0) bp[c] = (c < NCLS ? b[c] : 0.f) + r[0] + r[1] + r[2] + r[3];
}

// ---------------------------------------------------------------------------
// Kernel 3 (fused GEMM): out = BN((P-G)^2) @ W'^T + b', A-tile generated
// in-kernel. M=16384, N=768, K=2048. BK=64, XOR-swizzled f16 LDS tiles.
// Each 128-row M-tile has constant p = mtile>>1; rows are g = (mtile&1)*128+r.
// A-path: G f32 prefetched to regs one kstep ahead (issued after mid-barrier,
//         latency hidden under MFMA); (p-g)^2 -> f16 packed -> ds_write_b128
//         into swizzled slot (writer-side swizzle, direct control).
// B-path: Wp f16 via global_load_lds, issued at loop top so its L2 latency
//         overlaps the A-gen VALU phase before the mid-barrier drain.
// ---------------------------------------------------------------------------
__global__ __launch_bounds__(256, 3)
void gemm_fused_kernel(const float* __restrict__ P, const float* __restrict__ G,
                       const unsigned short* __restrict__ Wp,
                       const float* __restrict__ bp, float* __restrict__ out) {
  __shared__ unsigned short As[128 * 64];  // 16 KB: f16 (p-g)^2 tile
  __shared__ unsigned short Bs[128 * 64];  // 16 KB: f16 W' tile
  __shared__ float Ps[FEAT];               // 8 KB: this block's P row (f32)

  const int tid = threadIdx.x;
  const int lane = tid & 63, wave = tid >> 6;
  const int mtile = blockIdx.x, ntile = blockIdx.y;
  const int p = mtile >> 1;

  // staging roles: thread t -> LDS rows srow+32j, slot t&7; slot s of row r
  // holds global k-chunk s^(r&7)  => this thread sources chunk sch.
  const int srow = tid >> 3;                      // 0..31
  const int sch = (tid & 7) ^ (srow & 7);         // source k-chunk
  const float* gp = G + (size_t)((mtile & 1) * 128 + srow) * FEAT + sch * 8;
  const unsigned short* bg = Wp + (size_t)(ntile * 128 + srow) * FEAT + sch * 8;
  unsigned short* asw = As + srow * 64 + (tid & 7) * 8;  // ds_write dest (16B aligned)
  char* blds = (char*)Bs + wave * 1024;                  // wave-uniform; HW adds lane*16

  // prologue: P row -> LDS (f32); prefetch G regs for k0=0
  {
    const float4* psrc = (const float4*)(P + (size_t)p * FEAT) + tid * 2;
    float4 pa = psrc[0], pb = psrc[1];
    float4* pd = (float4*)Ps + tid * 2;
    pd[0] = pa; pd[1] = pb;
  }
  float4 g0[4], g1[4];
#pragma unroll
  for (int j = 0; j < 4; ++j) {
    const float4* gs = (const float4*)(gp + (size_t)j * 32 * FEAT);
    g0[j] = gs[0]; g1[j] = gs[1];
  }

  f32x4 acc[4][4];
#pragma unroll
  for (int mi = 0; mi < 4; ++mi)
#pragma unroll
    for (int ni = 0; ni < 4; ++ni) acc[mi][ni] = (f32x4){0.f, 0.f, 0.f, 0.f};

  const int wm = (wave & 1) * 64, wn = (wave >> 1) * 64;
  const int frow = lane & 15, fsw = lane & 7, fk = lane >> 4;  // fragment roles

  __syncthreads();  // Ps visible to all waves (also drains k0=0 G prefetch)

  for (int k0 = 0; k0 < FEAT; k0 += 64) {
    // B tile: async global->LDS; L2-hot after first mtile sweep
#pragma unroll
    for (int j = 0; j < 4; ++j)
      __builtin_amdgcn_global_load_lds(
          (const __attribute__((address_space(1))) void*)(bg + k0 + (size_t)j * 32 * FEAT),
          (__attribute__((address_space(3))) void*)(blds + j * 4096), 16, 0, 0);

    // A tile: (p-g)^2 -> f16 from prefetched G regs + LDS P row
    const float* pr = Ps + k0 + sch * 8;
    float4 p0 = *(const float4*)pr;
    float4 p1 = *(const float4*)(pr + 4);
#pragma unroll
    for (int j = 0; j < 4; ++j) {
      float d0 = p0.x - g0[j].x, d1 = p0.y - g0[j].y;
      float d2 = p0.z - g0[j].z, d3 = p0.w - g0[j].w;
      float d4 = p1.x - g1[j].x, d5 = p1.y - g1[j].y;
      float d6 = p1.z - g1[j].z, d7 = p1.w - g1[j].w;
      uint4 u;
      u.x = (unsigned int)f2h_u(d0 * d0) | ((unsigned int)f2h_u(d1 * d1) << 16);
      u.y = (unsigned int)f2h_u(d2 * d2) | ((unsigned int)f2h_u(d3 * d3) << 16);
      u.z = (unsigned int)f2h_u(d4 * d4) | ((unsigned int)f2h_u(d5 * d5) << 16);
      u.w = (unsigned int)f2h_u(d6 * d6) | ((unsigned int)f2h_u(d7 * d7) << 16);
      *(uint4*)(asw + j * 32 * 64) = u;
    }
    __syncthreads();  // drain: A ds_writes (lgkm) + B global_load_lds (vmcnt)

    // prefetch next G tile into regs; latency hides under the MFMA phase,
    // drained by the end-of-loop barrier.
    if (k0 + 64 < FEAT) {
#pragma unroll
      for (int j = 0; j < 4; ++j) {
        const float4* gs = (const float4*)(gp + k0 + 64 + (size_t)j * 32 * FEAT);
        g0[j] = gs[0]; g1[j] = gs[1];
      }
    }

#pragma unroll
    for (int kk = 0; kk < 2; ++kk) {
      const int slot = (kk * 4 + fk) ^ fsw;  // LDS slot holding k-chunk kk*4+fk
      f16x8 af[4], bf[4];
#pragma unroll
      for (int mi = 0; mi < 4; ++mi)
        af[mi] = *(const f16x8*)(As + (wm + mi * 16 + frow) * 64 + slot * 8);
#pragma unroll
      for (int ni = 0; ni < 4; ++ni)
        bf[ni] = *(const f16x8*)(Bs + (wn + ni * 16 + frow) * 64 + slot * 8);
#pragma unroll
      for (int mi = 0; mi < 4; ++mi)
#pragma unroll
        for (int ni = 0; ni < 4; ++ni)
          acc[mi][ni] = __builtin_amdgcn_mfma_f32_16x16x32_f16(af[mi], bf[ni], acc[mi][ni], 0, 0, 0);
    }
    __syncthreads();  // MFMA reads done; LDS free for next stage
  }

  // epilogue: C/D layout col=lane&15, row=(lane>>4)*4+reg; undo WSCALE, add b'
  const int col0 = ntile * 128 + wn + (lane & 15);
  const int row0 = mtile * 128 + wm + ((lane >> 4) << 2);
#pragma unroll
  for (int ni = 0; ni < 4; ++ni) {
    int col = col0 + ni * 16;
    if (col >= NCLS) continue;
    float bv = bp[col];
#pragma unroll
    for (int mi = 0; mi < 4; ++mi) {
      int row = row0 + mi * 16;
#pragma unroll
      for (int r = 0; r < 4; ++r)
        out[(size_t)(row + r) * NCLS + col] = acc[mi][ni][r] * (1.0f / WSCALE) + bv;
    }
  }
}

// ---------------------------------------------------------------------------
extern "C" void kernel_launch(void* const* d_in, const int* in_sizes, int n_in,
                              void* d_out, int out_size, void* d_ws, size_t ws_size,
                              hipStream_t stream) {
  const float* P = (const float*)d_in[0];
  const float* G = (const float*)d_in[1];
  const float* gamma = (const float*)d_in[2];
  const float* beta = (const float*)d_in[3];
  const float* W = (const float*)d_in[4];
  const float* b = (const float*)d_in[5];
  float* out = (float*)d_out;

  float* st = (float*)d_ws;                           // s[2048], t[2048]
  float* bp = st + 2 * FEAT;                          // b'[768]
  unsigned short* Wp = (unsigned short*)(bp + NPAD);  // f16 W' [768, 2048]

  hipLaunchKernelGGL(stats_kernel, dim3(64), dim3(256), 0, stream, P, G, gamma, beta, st);
  hipLaunchKernelGGL(prepw_kernel, dim3(NPAD), dim3(256), 0, stream, W, b, st, Wp, bp);
  hipLaunchKernelGGL(gemm_fused_kernel, dim3(128, 6), dim3(256), 0, stream, P, G, Wp, bp, out);
}